// Round 4
// baseline (767.666 us; speedup 1.0000x reference)
//
#include <hip/hip_runtime.h>
#include <hip/hip_bf16.h>

// GroupQuantLinear: y[m,n] = sum_k x[m,k] * (q[n,k]*s[n,g]+b[n,g]) + bias[n]
// M=4096, N=16384, K=4096, G=16 (group=256 k), nibbles packed in bits 0-15 of int32.
//
// Round 4: keep W 4-bit into the GEMM.
//   1) cvtA:    fp32 A -> bf16 wsA [M][K]
//   2) repackW: int32 words -> dense u16 nibble stream wsQ (4 nibbles/u16)
//   3) gql_gemm_q256: 256x256xBK64, 8 waves; A via global_load_lds (dbuf,
//      pre-swizzled source); B-packed global->regs (prefetch 1 tile) ->
//      dequant once per tile into shared sB (fma in fp32, f2bf) -> MFMA.
//      2 raw barriers/iter, vmcnt(0) only at iter end (issue-to-wait = full iter).
// Fallbacks: round-2 bf16-predecode 128^2 kernel; round-1 fused kernel.

typedef short bf16x8 __attribute__((ext_vector_type(8)));
typedef float f32x4 __attribute__((ext_vector_type(4)));
typedef unsigned short u16;
typedef unsigned int u32;
typedef unsigned short u16x4 __attribute__((ext_vector_type(4)));
typedef unsigned short u16x8 __attribute__((ext_vector_type(8)));

#define BM 128
#define BN 128
#define BK 64
#define THREADS 256

static __device__ __forceinline__ u16 f2bf(float f) {
    __hip_bfloat16 h = __float2bfloat16(f);
    return __builtin_bit_cast(u16, h);
}

// ---------------- predecode kernels ----------------

__global__ void cvtA_kernel(const float* __restrict__ A, u16* __restrict__ wsA,
                            size_t n8) {
    size_t i = (size_t)blockIdx.x * blockDim.x + threadIdx.x;
    if (i >= n8) return;
    const float4 v0 = *(const float4*)(A + i * 8);
    const float4 v1 = *(const float4*)(A + i * 8 + 4);
    u16x8 h;
    h[0] = f2bf(v0.x); h[1] = f2bf(v0.y); h[2] = f2bf(v0.z); h[3] = f2bf(v0.w);
    h[4] = f2bf(v1.x); h[5] = f2bf(v1.y); h[6] = f2bf(v1.z); h[7] = f2bf(v1.w);
    *(u16x8*)(wsA + i * 8) = h;
}

// nibbles live in bits 0-15 of each int32 -> dense stream is just the low u16
__global__ void repackW_kernel(const int* __restrict__ Wp, u16* __restrict__ wsQ,
                               size_t n8) {
    size_t t = (size_t)blockIdx.x * blockDim.x + threadIdx.x;
    if (t >= n8) return;
    const int4 a = *(const int4*)(Wp + t * 8);
    const int4 b = *(const int4*)(Wp + t * 8 + 4);
    u16x8 h;
    h[0] = (u16)a.x; h[1] = (u16)a.y; h[2] = (u16)a.z; h[3] = (u16)a.w;
    h[4] = (u16)b.x; h[5] = (u16)b.y; h[6] = (u16)b.z; h[7] = (u16)b.w;
    *(u16x8*)(wsQ + t * 8) = h;
}

__global__ void deqW_kernel(const int* __restrict__ Wp, const float* __restrict__ Ws,
                            const float* __restrict__ Wb, u16* __restrict__ wsW,
                            int K, int G, int gshift, int kgshift, size_t n8) {
    size_t t = (size_t)blockIdx.x * blockDim.x + threadIdx.x;
    if (t >= n8) return;
    const int n  = (int)(t >> kgshift);
    const int kg = (int)(t & ((1u << kgshift) - 1));
    const int k  = kg << 3;
    const int g  = k >> gshift;
    const float s = Ws[n * G + g];
    const float b = Wb[n * G + g];
    const int2 w2 = *(const int2*)(Wp + (size_t)n * (K >> 2) + (k >> 2));
    u16x8 h;
    #pragma unroll
    for (int j = 0; j < 4; ++j)
        h[j]     = f2bf(fmaf((float)((w2.x >> (4 * j)) & 0xF), s, b));
    #pragma unroll
    for (int j = 0; j < 4; ++j)
        h[4 + j] = f2bf(fmaf((float)((w2.y >> (4 * j)) & 0xF), s, b));
    *(u16x8*)(wsW + ((size_t)n << (kgshift + 3)) + k) = h;
}

// ---------------- 256x256 fused-dequant bf16 GEMM ----------------

__global__ __launch_bounds__(512, 2)
void gql_gemm_q256(const u16* __restrict__ wsA,  // [M][K] bf16
                   const u16* __restrict__ wsQ,  // [N][K/4] dense nibbles
                   const float* __restrict__ Ws, // [N][G]
                   const float* __restrict__ Wb, // [N][G]
                   const float* __restrict__ Bias,
                   float* __restrict__ Out,      // [M][N] fp32
                   int M, int N, int K, int G, int gshift)
{
    __shared__ __align__(16) u16 sA[2][256 * 64];  // 64 KB, dbuf, gload_lds
    __shared__ __align__(16) u16 sB[256 * 64];     // 32 KB, dequant target

    const int tid  = threadIdx.x;
    const int lane = tid & 63;
    const int wid  = tid >> 6;     // 0..7
    const int wm   = wid >> 2;     // 0..1
    const int wn   = wid & 3;      // 0..3

    const int nwg = gridDim.x;
    int wg = blockIdx.x;
    if ((nwg & 7) == 0) wg = (wg & 7) * (nwg >> 3) + (wg >> 3);
    const int nt = N / 256;
    const int m0 = (wg / nt) * 256;
    const int n0 = (wg % nt) * 256;

    // A staging (validated): wave covers 8 rows x 64 k per inst, linear LDS,
    // source pre-swizzled so swizzled ds_read is conflict-free.
    const int st_row = wid * 8 + (lane >> 3);
    const int gsrc   = ((lane & 7) ^ (lane >> 3)) << 3;

    // B-packed per-thread: half a row (32 k = 16B) per tile
    const int qrow  = tid >> 1;    // 0..255
    const int qhalf = tid & 1;
    const u16* qbase = wsQ + (size_t)(n0 + qrow) * (K >> 2) + qhalf * 8;
    const float* wsrow = Ws + (size_t)(n0 + qrow) * G;
    const float* wbrow = Wb + (size_t)(n0 + qrow) * G;
    const int qldsbase = qrow * 128;
    const int qswz = (qrow & 7) << 4;

    const int fr = lane & 15;
    const int fq = lane >> 4;

    f32x4 acc[8][4] = {};

    const int NT = K / 64;

    auto stageA = [&](int t, int buf) {
        const int k0 = t * 64;
        #pragma unroll
        for (int s = 0; s < 4; ++s) {
            const int r = s * 64 + st_row;
            const u16* srcA = wsA + (size_t)(m0 + r) * K + k0 + gsrc;
            __builtin_amdgcn_global_load_lds(
                (const __attribute__((address_space(1))) void*)srcA,
                (__attribute__((address_space(3))) void*)&sA[buf][(s * 64 + wid * 8) * 64],
                16, 0, 0);
        }
    };

    // prologue: tile 0 in flight, then drain + barrier
    stageA(0, 0);
    int4 bq = *(const int4*)qbase;   // tile 0 packed B
    __builtin_amdgcn_sched_barrier(0);
    asm volatile("s_waitcnt vmcnt(0)" ::: "memory");
    __builtin_amdgcn_s_barrier();
    asm volatile("" ::: "memory");

    int cur = 0;
    for (int t = 0; t < NT; ++t) {
        // (1) prefetch next tile (A -> LDS dbuf, Bq -> regs)
        int4 bqn = bq;
        if (t + 1 < NT) {
            stageA(t + 1, cur ^ 1);
            bqn = *(const int4*)(qbase + (size_t)(t + 1) * 16);
        }

        // (2) dequant this tile's packed B -> sB (old readers done: entry barrier)
        {
            const int g = (t * 64) >> gshift;
            const float sc = wsrow[g];
            const float bi = wbrow[g];
            const u32 w[4] = {(u32)bq.x, (u32)bq.y, (u32)bq.z, (u32)bq.w};
            #pragma unroll
            for (int d = 0; d < 4; ++d) {
                u16x8 h;
                #pragma unroll
                for (int j = 0; j < 4; ++j)
                    h[j]     = f2bf(fmaf((float)((w[d] >> (4 * j)) & 0xF), sc, bi));
                #pragma unroll
                for (int j = 0; j < 4; ++j)
                    h[4 + j] = f2bf(fmaf((float)(((w[d] >> 16) >> (4 * j)) & 0xF), sc, bi));
                const int byte = ((qhalf * 64 + d * 16) ^ qswz);
                *(u16x8*)((char*)sB + qldsbase + byte) = h;
            }
        }

        // (3)(4) my ds_writes done -> barrier -> everyone's sB visible
        asm volatile("s_waitcnt lgkmcnt(0)" ::: "memory");
        __builtin_amdgcn_sched_barrier(0);
        __builtin_amdgcn_s_barrier();
        asm volatile("" ::: "memory");

        // (5) compute tile t
        #pragma unroll
        for (int ks = 0; ks < 2; ++ks) {
            const int kx = ((((ks << 2) + fq) ^ (fr & 7)) << 4);
            bf16x8 af[8], bfg[4];
            #pragma unroll
            for (int i = 0; i < 8; ++i) {
                const int row = wm * 128 + i * 16 + fr;
                af[i] = *(const bf16x8*)((const char*)&sA[cur][0] + row * 128 + kx);
            }
            #pragma unroll
            for (int j = 0; j < 4; ++j) {
                const int row = wn * 64 + j * 16 + fr;
                bfg[j] = *(const bf16x8*)((const char*)sB + row * 128 + kx);
            }
            __builtin_amdgcn_s_setprio(1);
            #pragma unroll
            for (int i = 0; i < 8; ++i)
                #pragma unroll
                for (int j = 0; j < 4; ++j)
                    acc[i][j] = __builtin_amdgcn_mfma_f32_16x16x32_bf16(
                        af[i], bfg[j], acc[i][j], 0, 0, 0);
            __builtin_amdgcn_s_setprio(0);
        }

        // (6)(7) next tile landed -> barrier (loads issued a full iter ago)
        __builtin_amdgcn_sched_barrier(0);
        asm volatile("s_waitcnt vmcnt(0)" ::: "memory");
        __builtin_amdgcn_s_barrier();
        asm volatile("" ::: "memory");

        cur ^= 1;
        bq = bqn;
    }

    // epilogue: D row = 4*fq + r (m), col = fr (n)
    #pragma unroll
    for (int j = 0; j < 4; ++j) {
        const int n = n0 + wn * 64 + j * 16 + fr;
        const float bv = Bias[n];
        #pragma unroll
        for (int i = 0; i < 8; ++i) {
            const int mb = m0 + wm * 128 + i * 16 + (fq << 2);
            #pragma unroll
            for (int r = 0; r < 4; ++r)
                Out[(size_t)(mb + r) * N + n] = acc[i][j][r] + bv;
        }
    }
}

// ---------------- round-2 128x128 kernel (validated fallback) ----------------

__global__ __launch_bounds__(THREADS, 2)
void gql_gemm_pre(const u16* __restrict__ wsA,
                  const u16* __restrict__ wsW,
                  const float* __restrict__ Bias,
                  float* __restrict__ Out,
                  int M, int N, int K)
{
    __shared__ __align__(16) u16 sA[BM * BK];
    __shared__ __align__(16) u16 sB[BN * BK];

    const int tid  = threadIdx.x;
    const int lane = tid & 63;
    const int wid  = tid >> 6;

    const int nwg = gridDim.x;
    int wg = blockIdx.x;
    if ((nwg & 7) == 0) wg = (wg & 7) * (nwg >> 3) + (wg >> 3);
    const int nt     = N / BN;
    const int m0 = (wg / nt) * BM;
    const int n0 = (wg % nt) * BN;

    const int st_r  = (lane >> 3);
    const int st_g  = lane & 7;

    const int wr = (wid >> 1) << 6;
    const int wc = (wid & 1) << 6;
    const int fr = lane & 15;
    const int fq = lane >> 4;

    f32x4 acc[4][4] = {};

    for (int k0 = 0; k0 < K; k0 += BK) {
        __syncthreads();

        #pragma unroll
        for (int i = 0; i < 4; ++i) {
            const int r = wid * 32 + i * 8 + st_r;
            const int gsrc = (st_g ^ (r & 7)) << 3;
            const u16* srcA = wsA + (size_t)(m0 + r) * K + k0 + gsrc;
            const u16* srcB = wsW + (size_t)(n0 + r) * K + k0 + gsrc;
            __builtin_amdgcn_global_load_lds(
                (const __attribute__((address_space(1))) void*)srcA,
                (__attribute__((address_space(3))) void*)&sA[(wid * 32 + i * 8) * BK],
                16, 0, 0);
            __builtin_amdgcn_global_load_lds(
                (const __attribute__((address_space(1))) void*)srcB,
                (__attribute__((address_space(3))) void*)&sB[(wid * 32 + i * 8) * BK],
                16, 0, 0);
        }

        __syncthreads();

        #pragma unroll
        for (int sub = 0; sub < 2; ++sub) {
            const int kch = (sub << 2) + fq;
            bf16x8 af[4], bfg[4];
            #pragma unroll
            for (int i = 0; i < 4; ++i) {
                const int row = wr + i * 16 + fr;
                af[i] = *(const bf16x8*)((const char*)sA + row * (BK * 2)
                                         + (((kch ^ (row & 7)) << 4)));
            }
            #pragma unroll
            for (int j = 0; j < 4; ++j) {
                const int row = wc + j * 16 + fr;
                bfg[j] = *(const bf16x8*)((const char*)sB + row * (BK * 2)
                                          + (((kch ^ (row & 7)) << 4)));
            }
            #pragma unroll
            for (int i = 0; i < 4; ++i)
                #pragma unroll
                for (int j = 0; j < 4; ++j)
                    acc[i][j] = __builtin_amdgcn_mfma_f32_16x16x32_bf16(
                        af[i], bfg[j], acc[i][j], 0, 0, 0);
        }
    }

    #pragma unroll
    for (int j = 0; j < 4; ++j) {
        const int n = n0 + wc + j * 16 + fr;
        const float bv = Bias[n];
        #pragma unroll
        for (int i = 0; i < 4; ++i) {
            const int mb = m0 + wr + i * 16 + (fq << 2);
            #pragma unroll
            for (int r = 0; r < 4; ++r)
                Out[(size_t)(mb + r) * N + n] = acc[i][j][r] + bv;
        }
    }
}

// ---------------- round-1 fused fallback ----------------

__global__ __launch_bounds__(THREADS, 2)
void gql_gemm(const float* __restrict__ A,
              const int* __restrict__ Wp,
              const float* __restrict__ Ws,
              const float* __restrict__ Wb,
              const float* __restrict__ Bias,
              float* __restrict__ Out,
              int M, int N, int K, int G, int gshift)
{
    __shared__ __align__(16) u16 sA[BM * BK];
    __shared__ __align__(16) u16 sB[BN * BK];

    const int tid  = threadIdx.x;
    const int lane = tid & 63;
    const int wid  = tid >> 6;

    const int nwg = gridDim.x;
    int wg = blockIdx.x;
    if ((nwg & 7) == 0) wg = (wg & 7) * (nwg >> 3) + (wg >> 3);
    const int nt     = N / BN;
    const int m0 = (wg / nt) * BM;
    const int n0 = (wg % nt) * BN;

    const int wpr = K >> 2;

    const int a_r = tid >> 4;
    const int a_c = (tid & 15) << 2;
    const int b_r = tid >> 3;
    const int b_w = (tid & 7) << 1;

    const int wr = (wid >> 1) << 6;
    const int wc = (wid & 1) << 6;
    const int fr = lane & 15;
    const int fq = lane >> 4;

    f32x4 acc[4][4] = {};

    for (int k0 = 0; k0 < K; k0 += BK) {
        __syncthreads();

        #pragma unroll
        for (int it = 0; it < 8; ++it) {
            const int row = it * 16 + a_r;
            const float4 v = *(const float4*)(A + (size_t)(m0 + row) * K + (k0 + a_c));
            u16x4 h;
            h[0] = f2bf(v.x); h[1] = f2bf(v.y); h[2] = f2bf(v.z); h[3] = f2bf(v.w);
            const int byte = (a_c << 1) ^ ((row & 7) << 4);
            *(u16x4*)((char*)sA + row * (BK * 2) + byte) = h;
        }

        const int g = k0 >> gshift;
        #pragma unroll
        for (int it = 0; it < 4; ++it) {
            const int row = it * 32 + b_r;
            const int gn  = n0 + row;
            const int2 w2 = *(const int2*)(Wp + (size_t)gn * wpr + (k0 >> 2) + b_w);
            const float s = Ws[gn * G + g];
            const float b = Wb[gn * G + g];
            u16x8 h;
            #pragma unroll
            for (int j = 0; j < 4; ++j)
                h[j]     = f2bf(fmaf((float)((w2.x >> (4 * j)) & 0xF), s, b));
            #pragma unroll
            for (int j = 0; j < 4; ++j)
                h[4 + j] = f2bf(fmaf((float)((w2.y >> (4 * j)) & 0xF), s, b));
            const int byte = (b_w << 3) ^ ((row & 7) << 4);
            *(u16x8*)((char*)sB + row * (BK * 2) + byte) = h;
        }

        __syncthreads();

        #pragma unroll
        for (int sub = 0; sub < 2; ++sub) {
            const int kch = (sub << 2) + fq;
            bf16x8 af[4], bfg[4];
            #pragma unroll
            for (int i = 0; i < 4; ++i) {
                const int row = wr + i * 16 + fr;
                af[i] = *(const bf16x8*)((const char*)sA + row * (BK * 2)
                                         + ((kch << 4) ^ ((row & 7) << 4)));
            }
            #pragma unroll
            for (int j = 0; j < 4; ++j) {
                const int row = wc + j * 16 + fr;
                bfg[j] = *(const bf16x8*)((const char*)sB + row * (BK * 2)
                                          + ((kch << 4) ^ ((row & 7) << 4)));
            }
            #pragma unroll
            for (int i = 0; i < 4; ++i)
                #pragma unroll
                for (int j = 0; j < 4; ++j)
                    acc[i][j] = __builtin_amdgcn_mfma_f32_16x16x32_bf16(
                        af[i], bfg[j], acc[i][j], 0, 0, 0);
        }
    }

    #pragma unroll
    for (int j = 0; j < 4; ++j) {
        const int n = n0 + wc + j * 16 + fr;
        const float bv = Bias[n];
        #pragma unroll
        for (int i = 0; i < 4; ++i) {
            const int mb = m0 + wr + i * 16 + (fq << 2);
            #pragma unroll
            for (int r = 0; r < 4; ++r)
                Out[(size_t)(mb + r) * N + n] = acc[i][j][r] + bv;
        }
    }
}

extern "C" void kernel_launch(void* const* d_in, const int* in_sizes, int n_in,
                              void* d_out, int out_size, void* d_ws, size_t ws_size,
                              hipStream_t stream) {
    const float* A    = (const float*)d_in[0];
    const int*   Wp   = (const int*)d_in[1];
    const float* Ws   = (const float*)d_in[2];
    const float* Wb   = (const float*)d_in[3];
    const float* Bias = (const float*)d_in[4];
    float* Out = (float*)d_out;

    const int OUT  = in_sizes[4];
    const int OG   = in_sizes[2];          // OUT * G
    const int G    = OG / OUT;             // 16
    const int cols = in_sizes[1] / OG;     // 64
    const int IN   = G * cols * 4;         // 4096
    const int M    = in_sizes[0] / IN;     // 4096

    const int gk = IN / G;                 // 256
    int gshift = 0;
    while ((1 << gshift) < gk) ++gshift;   // 8

    const size_t needA = (size_t)M * IN * 2;       // bf16 A
    const size_t needQ = (size_t)OUT * IN / 2;     // dense nibbles (u16 stream)
    const size_t needW = (size_t)OUT * IN * 2;     // bf16 W (fallback)

    if (ws_size >= needA + needQ && (IN & 255) == 0 && gshift >= 6 &&
        (M % 256) == 0 && (OUT % 256) == 0 && ((1 << gshift) == gk)) {
        // primary: 4-bit-to-the-end path
        u16* wsA = (u16*)d_ws;
        u16* wsQ = (u16*)((char*)d_ws + needA);

        const size_t nA8 = (size_t)M * IN / 8;
        cvtA_kernel<<<(unsigned)((nA8 + 255) / 256), 256, 0, stream>>>(A, wsA, nA8);

        const size_t nQ8 = (size_t)OUT * IN / 4 / 8;   // u16 words / 8
        repackW_kernel<<<(unsigned)((nQ8 + 255) / 256), 256, 0, stream>>>(Wp, wsQ, nQ8);

        dim3 grid((M / 256) * (OUT / 256));
        gql_gemm_q256<<<grid, 512, 0, stream>>>(wsA, wsQ, Ws, Wb, Bias, Out,
                                                M, OUT, IN, G, gshift);
    } else if (ws_size >= needA + needW && (IN & 7) == 0 &&
               (M % 128) == 0 && (OUT % 128) == 0 && (IN % 64) == 0) {
        u16* wsA = (u16*)d_ws;
        u16* wsW = (u16*)((char*)d_ws + needA);

        const size_t nA8 = (size_t)M * IN / 8;
        cvtA_kernel<<<(unsigned)((nA8 + 255) / 256), 256, 0, stream>>>(A, wsA, nA8);

        int kgshift = 0;
        while ((1 << kgshift) < (IN >> 3)) ++kgshift;
        const size_t nW8 = (size_t)OUT * IN / 8;
        deqW_kernel<<<(unsigned)((nW8 + 255) / 256), 256, 0, stream>>>(
            Wp, Ws, Wb, wsW, IN, G, gshift, kgshift, nW8);

        dim3 grid((M / BM) * (OUT / BN));
        gql_gemm_pre<<<grid, THREADS, 0, stream>>>(wsA, wsW, Bias, Out, M, OUT, IN);
    } else {
        dim3 grid((M / BM) * (OUT / BN));
        gql_gemm<<<grid, THREADS, 0, stream>>>(A, Wp, Ws, Wb, Bias, Out,
                                               M, OUT, IN, G, gshift);
    }
}

// Round 5
// 727.971 us; speedup vs baseline: 1.0545x; 1.0545x over previous
//
#include <hip/hip_runtime.h>
#include <hip/hip_bf16.h>

// GroupQuantLinear: y[m,n] = sum_k x[m,k] * (q[n,k]*s[n,g]+b[n,g]) + bias[n]
// M=4096, N=16384, K=4096, G=16.
//
// Round 5: bf16 predecode (A,W -> d_ws) + 256x256 8-phase-style GEMM:
//   4 quadrant phases per K-tile (16 MFMA clusters), per-phase {ds_read
//   subtile; stage 1 half-tile of t+1; raw barrier; setprio MFMA cluster},
//   counted vmcnt(2) at tile entry (never 0 in loop), exit barrier per tile.
// Fallbacks: round-2 128^2 kernel; round-1 fused kernel.

typedef short bf16x8 __attribute__((ext_vector_type(8)));
typedef float f32x4 __attribute__((ext_vector_type(4)));
typedef unsigned short u16;
typedef unsigned short u16x4 __attribute__((ext_vector_type(4)));
typedef unsigned short u16x8 __attribute__((ext_vector_type(8)));

#define BM 128
#define BN 128
#define BK 64
#define THREADS 256

static __device__ __forceinline__ u16 f2bf(float f) {
    __hip_bfloat16 h = __float2bfloat16(f);
    return __builtin_bit_cast(u16, h);
}

// ---------------- predecode kernels ----------------

__global__ void cvtA_kernel(const float* __restrict__ A, u16* __restrict__ wsA,
                            size_t n8) {
    size_t i = (size_t)blockIdx.x * blockDim.x + threadIdx.x;
    if (i >= n8) return;
    const float4 v0 = *(const float4*)(A + i * 8);
    const float4 v1 = *(const float4*)(A + i * 8 + 4);
    u16x8 h;
    h[0] = f2bf(v0.x); h[1] = f2bf(v0.y); h[2] = f2bf(v0.z); h[3] = f2bf(v0.w);
    h[4] = f2bf(v1.x); h[5] = f2bf(v1.y); h[6] = f2bf(v1.z); h[7] = f2bf(v1.w);
    *(u16x8*)(wsA + i * 8) = h;
}

__global__ void deqW_kernel(const int* __restrict__ Wp, const float* __restrict__ Ws,
                            const float* __restrict__ Wb, u16* __restrict__ wsW,
                            int K, int G, int gshift, int kgshift, size_t n8) {
    size_t t = (size_t)blockIdx.x * blockDim.x + threadIdx.x;
    if (t >= n8) return;
    const int n  = (int)(t >> kgshift);
    const int kg = (int)(t & ((1u << kgshift) - 1));
    const int k  = kg << 3;
    const int g  = k >> gshift;
    const float s = Ws[n * G + g];
    const float b = Wb[n * G + g];
    const int2 w2 = *(const int2*)(Wp + (size_t)n * (K >> 2) + (k >> 2));
    u16x8 h;
    #pragma unroll
    for (int j = 0; j < 4; ++j)
        h[j]     = f2bf(fmaf((float)((w2.x >> (4 * j)) & 0xF), s, b));
    #pragma unroll
    for (int j = 0; j < 4; ++j)
        h[4 + j] = f2bf(fmaf((float)((w2.y >> (4 * j)) & 0xF), s, b));
    *(u16x8*)(wsW + ((size_t)n << (kgshift + 3)) + k) = h;
}

// ---------------- 256x256 phased bf16 GEMM ----------------

__global__ __launch_bounds__(512, 2)
void gql_gemm_8p(const u16* __restrict__ wsA,  // [M][K] bf16
                 const u16* __restrict__ wsW,  // [N][K] bf16
                 const float* __restrict__ Bias,
                 float* __restrict__ Out,      // [M][N] fp32
                 int M, int N, int K)
{
    __shared__ __align__(16) u16 sA[2][256 * 64];  // 2 x 32 KB
    __shared__ __align__(16) u16 sB[2][256 * 64];  // 2 x 32 KB

    const int tid  = threadIdx.x;
    const int lane = tid & 63;
    const int wid  = tid >> 6;     // 0..7
    const int wm   = wid >> 2;     // 0..1
    const int wn   = wid & 3;      // 0..3

    const int nwg = gridDim.x;
    int wg = blockIdx.x;
    if ((nwg & 7) == 0) wg = (wg & 7) * (nwg >> 3) + (wg >> 3);
    const int nt = N / 256;
    const int m0 = (wg / nt) * 256;
    const int n0 = (wg % nt) * 256;

    // staging: per inst a wave covers 8 rows x 64 k, linear LDS dest;
    // global source pre-swizzled (granule ^= row&7) -> swizzled ds_read is
    // conflict-free (validated rounds 2-4: SQ_LDS_BANK_CONFLICT = 0).
    const int st_row = wid * 8 + (lane >> 3);
    const int gsrc   = ((lane & 7) ^ (lane >> 3)) << 3;

    const int fr = lane & 15;
    const int fq = lane >> 4;

    f32x4 acc[8][4] = {};

    const int NT = K / 64;

    // half: 0 -> rows 0..127 (s=0,1), 1 -> rows 128..255 (s=2,3); 2 insts each
    auto stageA_half = [&](int t, int buf, int half) {
        const int k0 = t * 64;
        #pragma unroll
        for (int s = half * 2; s < half * 2 + 2; ++s) {
            const int r = s * 64 + st_row;
            const u16* src = wsA + (size_t)(m0 + r) * K + k0 + gsrc;
            __builtin_amdgcn_global_load_lds(
                (const __attribute__((address_space(1))) void*)src,
                (__attribute__((address_space(3))) void*)&sA[buf][(s * 64 + wid * 8) * 64],
                16, 0, 0);
        }
    };
    auto stageB_half = [&](int t, int buf, int half) {
        const int k0 = t * 64;
        #pragma unroll
        for (int s = half * 2; s < half * 2 + 2; ++s) {
            const int r = s * 64 + st_row;
            const u16* src = wsW + (size_t)(n0 + r) * K + k0 + gsrc;
            __builtin_amdgcn_global_load_lds(
                (const __attribute__((address_space(1))) void*)src,
                (__attribute__((address_space(3))) void*)&sB[buf][(s * 64 + wid * 8) * 64],
                16, 0, 0);
        }
    };

    auto lds_row = [&](const u16* s, int row, int kx) -> bf16x8 {
        return *(const bf16x8*)((const char*)s + row * 128 + kx);
    };

    // prologue: tile 0 fully staged (8 loads outstanding)
    stageA_half(0, 0, 0); stageA_half(0, 0, 1);
    stageB_half(0, 0, 0); stageB_half(0, 0, 1);

    for (int t = 0; t < NT; ++t) {
        const int b  = t & 1;
        const int tn = (t + 1 < NT) ? (t + 1) : (NT - 1);  // clamp: in-bounds, dead buf

        // ---- tile entry: issue h0(t+1), wait tile t landed (counted), publish
        stageA_half(tn, b ^ 1, 0);                    // outstanding: 8(t) + 2
        __builtin_amdgcn_sched_barrier(0);
        asm volatile("s_waitcnt vmcnt(2)" ::: "memory");
        __builtin_amdgcn_s_barrier();
        asm volatile("" ::: "memory");

        const int kx0 = ((fq ^ (fr & 7)) << 4);
        const int kx1 = (((4 + fq) ^ (fr & 7)) << 4);
        bf16x8 af[8], bfg[4];

        // ---- phase 0: ks=0, quadrant i=0..3 (8 ds_read) ----
        #pragma unroll
        for (int i = 0; i < 4; ++i)
            af[i] = lds_row(sA[b], wm * 128 + i * 16 + fr, kx0);
        #pragma unroll
        for (int j = 0; j < 4; ++j)
            bfg[j] = lds_row(sB[b], wn * 64 + j * 16 + fr, kx0);
        stageA_half(tn, b ^ 1, 1);
        __builtin_amdgcn_s_barrier();
        __builtin_amdgcn_s_setprio(1);
        #pragma unroll
        for (int i = 0; i < 4; ++i)
            #pragma unroll
            for (int j = 0; j < 4; ++j)
                acc[i][j] = __builtin_amdgcn_mfma_f32_16x16x32_bf16(
                    af[i], bfg[j], acc[i][j], 0, 0, 0);
        __builtin_amdgcn_s_setprio(0);

        // ---- phase 1: ks=0, quadrant i=4..7 (4 ds_read) ----
        #pragma unroll
        for (int i = 4; i < 8; ++i)
            af[i] = lds_row(sA[b], wm * 128 + i * 16 + fr, kx0);
        stageB_half(tn, b ^ 1, 0);
        __builtin_amdgcn_s_barrier();
        __builtin_amdgcn_s_setprio(1);
        #pragma unroll
        for (int i = 4; i < 8; ++i)
            #pragma unroll
            for (int j = 0; j < 4; ++j)
                acc[i][j] = __builtin_amdgcn_mfma_f32_16x16x32_bf16(
                    af[i], bfg[j], acc[i][j], 0, 0, 0);
        __builtin_amdgcn_s_setprio(0);

        // ---- phase 2: ks=1, quadrant i=0..3 (8 ds_read) ----
        #pragma unroll
        for (int i = 0; i < 4; ++i)
            af[i] = lds_row(sA[b], wm * 128 + i * 16 + fr, kx1);
        #pragma unroll
        for (int j = 0; j < 4; ++j)
            bfg[j] = lds_row(sB[b], wn * 64 + j * 16 + fr, kx1);
        stageB_half(tn, b ^ 1, 1);
        __builtin_amdgcn_s_barrier();
        __builtin_amdgcn_s_setprio(1);
        #pragma unroll
        for (int i = 0; i < 4; ++i)
            #pragma unroll
            for (int j = 0; j < 4; ++j)
                acc[i][j] = __builtin_amdgcn_mfma_f32_16x16x32_bf16(
                    af[i], bfg[j], acc[i][j], 0, 0, 0);
        __builtin_amdgcn_s_setprio(0);

        // ---- phase 3: ks=1, quadrant i=4..7 (4 ds_read) ----
        #pragma unroll
        for (int i = 4; i < 8; ++i)
            af[i] = lds_row(sA[b], wm * 128 + i * 16 + fr, kx1);
        __builtin_amdgcn_s_barrier();
        __builtin_amdgcn_s_setprio(1);
        #pragma unroll
        for (int i = 4; i < 8; ++i)
            #pragma unroll
            for (int j = 0; j < 4; ++j)
                acc[i][j] = __builtin_amdgcn_mfma_f32_16x16x32_bf16(
                    af[i], bfg[j], acc[i][j], 0, 0, 0);
        __builtin_amdgcn_s_setprio(0);

        // ---- tile exit: all waves' reads of buf b retired (lgkm waits
        // preceded the MFMAs) before anyone stages tile t+2 into buf b.
        asm volatile("" ::: "memory");
        __builtin_amdgcn_s_barrier();
        asm volatile("" ::: "memory");
    }

    asm volatile("s_waitcnt vmcnt(0)" ::: "memory");  // drain clamped tail stages

    // epilogue: D row = 4*fq + r (m), col = fr (n)  [validated R2-R4]
    #pragma unroll
    for (int j = 0; j < 4; ++j) {
        const int n = n0 + wn * 64 + j * 16 + fr;
        const float bv = Bias[n];
        #pragma unroll
        for (int i = 0; i < 8; ++i) {
            const int mb = m0 + wm * 128 + i * 16 + (fq << 2);
            #pragma unroll
            for (int r = 0; r < 4; ++r)
                Out[(size_t)(mb + r) * N + n] = acc[i][j][r] + bv;
        }
    }
}

// ---------------- round-2 128x128 kernel (validated fallback) ----------------

__global__ __launch_bounds__(THREADS, 2)
void gql_gemm_pre(const u16* __restrict__ wsA,
                  const u16* __restrict__ wsW,
                  const float* __restrict__ Bias,
                  float* __restrict__ Out,
                  int M, int N, int K)
{
    __shared__ __align__(16) u16 sA[BM * BK];
    __shared__ __align__(16) u16 sB[BN * BK];

    const int tid  = threadIdx.x;
    const int lane = tid & 63;
    const int wid  = tid >> 6;

    const int nwg = gridDim.x;
    int wg = blockIdx.x;
    if ((nwg & 7) == 0) wg = (wg & 7) * (nwg >> 3) + (wg >> 3);
    const int nt     = N / BN;
    const int m0 = (wg / nt) * BM;
    const int n0 = (wg % nt) * BN;

    const int st_r  = (lane >> 3);
    const int st_g  = lane & 7;

    const int wr = (wid >> 1) << 6;
    const int wc = (wid & 1) << 6;
    const int fr = lane & 15;
    const int fq = lane >> 4;

    f32x4 acc[4][4] = {};

    for (int k0 = 0; k0 < K; k0 += BK) {
        __syncthreads();

        #pragma unroll
        for (int i = 0; i < 4; ++i) {
            const int r = wid * 32 + i * 8 + st_r;
            const int gsrc = (st_g ^ (r & 7)) << 3;
            const u16* srcA = wsA + (size_t)(m0 + r) * K + k0 + gsrc;
            const u16* srcB = wsW + (size_t)(n0 + r) * K + k0 + gsrc;
            __builtin_amdgcn_global_load_lds(
                (const __attribute__((address_space(1))) void*)srcA,
                (__attribute__((address_space(3))) void*)&sA[(wid * 32 + i * 8) * BK],
                16, 0, 0);
            __builtin_amdgcn_global_load_lds(
                (const __attribute__((address_space(1))) void*)srcB,
                (__attribute__((address_space(3))) void*)&sB[(wid * 32 + i * 8) * BK],
                16, 0, 0);
        }

        __syncthreads();

        #pragma unroll
        for (int sub = 0; sub < 2; ++sub) {
            const int kch = (sub << 2) + fq;
            bf16x8 af[4], bfg[4];
            #pragma unroll
            for (int i = 0; i < 4; ++i) {
                const int row = wr + i * 16 + fr;
                af[i] = *(const bf16x8*)((const char*)sA + row * (BK * 2)
                                         + (((kch ^ (row & 7)) << 4)));
            }
            #pragma unroll
            for (int j = 0; j < 4; ++j) {
                const int row = wc + j * 16 + fr;
                bfg[j] = *(const bf16x8*)((const char*)sB + row * (BK * 2)
                                          + (((kch ^ (row & 7)) << 4)));
            }
            #pragma unroll
            for (int i = 0; i < 4; ++i)
                #pragma unroll
                for (int j = 0; j < 4; ++j)
                    acc[i][j] = __builtin_amdgcn_mfma_f32_16x16x32_bf16(
                        af[i], bfg[j], acc[i][j], 0, 0, 0);
        }
    }

    #pragma unroll
    for (int j = 0; j < 4; ++j) {
        const int n = n0 + wc + j * 16 + fr;
        const float bv = Bias[n];
        #pragma unroll
        for (int i = 0; i < 4; ++i) {
            const int mb = m0 + wr + i * 16 + (fq << 2);
            #pragma unroll
            for (int r = 0; r < 4; ++r)
                Out[(size_t)(mb + r) * N + n] = acc[i][j][r] + bv;
        }
    }
}

// ---------------- round-1 fused fallback ----------------

__global__ __launch_bounds__(THREADS, 2)
void gql_gemm(const float* __restrict__ A,
              const int* __restrict__ Wp,
              const float* __restrict__ Ws,
              const float* __restrict__ Wb,
              const float* __restrict__ Bias,
              float* __restrict__ Out,
              int M, int N, int K, int G, int gshift)
{
    __shared__ __align__(16) u16 sA[BM * BK];
    __shared__ __align__(16) u16 sB[BN * BK];

    const int tid  = threadIdx.x;
    const int lane = tid & 63;
    const int wid  = tid >> 6;

    const int nwg = gridDim.x;
    int wg = blockIdx.x;
    if ((nwg & 7) == 0) wg = (wg & 7) * (nwg >> 3) + (wg >> 3);
    const int nt     = N / BN;
    const int m0 = (wg / nt) * BM;
    const int n0 = (wg % nt) * BN;

    const int wpr = K >> 2;

    const int a_r = tid >> 4;
    const int a_c = (tid & 15) << 2;
    const int b_r = tid >> 3;
    const int b_w = (tid & 7) << 1;

    const int wr = (wid >> 1) << 6;
    const int wc = (wid & 1) << 6;
    const int fr = lane & 15;
    const int fq = lane >> 4;

    f32x4 acc[4][4] = {};

    for (int k0 = 0; k0 < K; k0 += BK) {
        __syncthreads();

        #pragma unroll
        for (int it = 0; it < 8; ++it) {
            const int row = it * 16 + a_r;
            const float4 v = *(const float4*)(A + (size_t)(m0 + row) * K + (k0 + a_c));
            u16x4 h;
            h[0] = f2bf(v.x); h[1] = f2bf(v.y); h[2] = f2bf(v.z); h[3] = f2bf(v.w);
            const int byte = (a_c << 1) ^ ((row & 7) << 4);
            *(u16x4*)((char*)sA + row * (BK * 2) + byte) = h;
        }

        const int g = k0 >> gshift;
        #pragma unroll
        for (int it = 0; it < 4; ++it) {
            const int row = it * 32 + b_r;
            const int gn  = n0 + row;
            const int2 w2 = *(const int2*)(Wp + (size_t)gn * wpr + (k0 >> 2) + b_w);
            const float s = Ws[gn * G + g];
            const float b = Wb[gn * G + g];
            u16x8 h;
            #pragma unroll
            for (int j = 0; j < 4; ++j)
                h[j]     = f2bf(fmaf((float)((w2.x >> (4 * j)) & 0xF), s, b));
            #pragma unroll
            for (int j = 0; j < 4; ++j)
                h[4 + j] = f2bf(fmaf((float)((w2.y >> (4 * j)) & 0xF), s, b));
            const int byte = (b_w << 3) ^ ((row & 7) << 4);
            *(u16x8*)((char*)sB + row * (BK * 2) + byte) = h;
        }

        __syncthreads();

        #pragma unroll
        for (int sub = 0; sub < 2; ++sub) {
            const int kch = (sub << 2) + fq;
            bf16x8 af[4], bfg[4];
            #pragma unroll
            for (int i = 0; i < 4; ++i) {
                const int row = wr + i * 16 + fr;
                af[i] = *(const bf16x8*)((const char*)sA + row * (BK * 2)
                                         + ((kch << 4) ^ ((row & 7) << 4)));
            }
            #pragma unroll
            for (int j = 0; j < 4; ++j) {
                const int row = wc + j * 16 + fr;
                bfg[j] = *(const bf16x8*)((const char*)sB + row * (BK * 2)
                                          + ((kch << 4) ^ ((row & 7) << 4)));
            }
            #pragma unroll
            for (int i = 0; i < 4; ++i)
                #pragma unroll
                for (int j = 0; j < 4; ++j)
                    acc[i][j] = __builtin_amdgcn_mfma_f32_16x16x32_bf16(
                        af[i], bfg[j], acc[i][j], 0, 0, 0);
        }
    }

    #pragma unroll
    for (int j = 0; j < 4; ++j) {
        const int n = n0 + wc + j * 16 + fr;
        const float bv = Bias[n];
        #pragma unroll
        for (int i = 0; i < 4; ++i) {
            const int mb = m0 + wr + i * 16 + (fq << 2);
            #pragma unroll
            for (int r = 0; r < 4; ++r)
                Out[(size_t)(mb + r) * N + n] = acc[i][j][r] + bv;
        }
    }
}

extern "C" void kernel_launch(void* const* d_in, const int* in_sizes, int n_in,
                              void* d_out, int out_size, void* d_ws, size_t ws_size,
                              hipStream_t stream) {
    const float* A    = (const float*)d_in[0];
    const int*   Wp   = (const int*)d_in[1];
    const float* Ws   = (const float*)d_in[2];
    const float* Wb   = (const float*)d_in[3];
    const float* Bias = (const float*)d_in[4];
    float* Out = (float*)d_out;

    const int OUT  = in_sizes[4];
    const int OG   = in_sizes[2];          // OUT * G
    const int G    = OG / OUT;             // 16
    const int cols = in_sizes[1] / OG;     // 64
    const int IN   = G * cols * 4;         // 4096
    const int M    = in_sizes[0] / IN;     // 4096

    const int gk = IN / G;                 // 256
    int gshift = 0;
    while ((1 << gshift) < gk) ++gshift;   // 8

    const size_t needA = (size_t)M * IN * 2;
    const size_t needW = (size_t)OUT * IN * 2;

    if (ws_size >= needA + needW && (IN & 7) == 0 &&
        (M % 128) == 0 && (OUT % 128) == 0 && (IN % 64) == 0) {
        u16* wsA = (u16*)d_ws;
        u16* wsW = (u16*)((char*)d_ws + needA);

        const size_t nA8 = (size_t)M * IN / 8;
        cvtA_kernel<<<(unsigned)((nA8 + 255) / 256), 256, 0, stream>>>(A, wsA, nA8);

        int kgshift = 0;
        while ((1 << kgshift) < (IN >> 3)) ++kgshift;
        const size_t nW8 = (size_t)OUT * IN / 8;
        deqW_kernel<<<(unsigned)((nW8 + 255) / 256), 256, 0, stream>>>(
            Wp, Ws, Wb, wsW, IN, G, gshift, kgshift, nW8);

        if ((M % 256) == 0 && (OUT % 256) == 0) {
            dim3 grid((M / 256) * (OUT / 256));
            gql_gemm_8p<<<grid, 512, 0, stream>>>(wsA, wsW, Bias, Out, M, OUT, IN);
        } else {
            dim3 grid((M / BM) * (OUT / BN));
            gql_gemm_pre<<<grid, THREADS, 0, stream>>>(wsA, wsW, Bias, Out,
                                                       M, OUT, IN);
        }
    } else {
        dim3 grid((M / BM) * (OUT / BN));
        gql_gemm<<<grid, THREADS, 0, stream>>>(A, Wp, Ws, Wb, Bias, Out,
                                               M, OUT, IN, G, gshift);
    }
}

// Round 6
// 522.849 us; speedup vs baseline: 1.4682x; 1.3923x over previous
//
#include <hip/hip_runtime.h>
#include <hip/hip_bf16.h>

// GroupQuantLinear: y[m,n] = sum_k x[m,k]*(q[n,k]*s[n,g]+b[n,g]) + bias[n]
// M=4096, N=16384, K=4096, G=16 (group = 256 k).
//
// Round 6: int8 path. Rationale: bf16 kernels are LDS-bytes-per-FLOP bound
// (192 ds_read_b128 + 64KB staged per 2483-cy MFMA step -> MfmaUtil pinned
// ~34% across 3 schedules). i8 MFMA = 2x rate, 1/2 bytes/FLOP.
//   wq[n,k] = round((q*s+b)/sw[n,g]),  sw = max(|b|,|15s+b|)/127  (exact lattice)
//   xq[m,k] = round(x / sx[m]),        sx = max|x[m,:]|/127
//   acc_i32 per 256-k group -> y += sw*acc ;  Out = sx[m]*y + bias[n]
// GEMM: 128x256 block, 8 waves (64x64 each), BK=128, dbuf LDS 96KB,
// counted vmcnt(6) + raw barriers (r3-validated), XOR-granule swizzle
// (validated: 0 bank conflicts in r2-r5).
// Fallbacks: r2 bf16-predecode 128^2 kernel; r1 fused kernel.

typedef short bf16x8 __attribute__((ext_vector_type(8)));
typedef float f32x4 __attribute__((ext_vector_type(4)));
typedef int i32x4 __attribute__((ext_vector_type(4)));
typedef int i32x16 __attribute__((ext_vector_type(16)));
typedef unsigned short u16;
typedef unsigned short u16x4 __attribute__((ext_vector_type(4)));
typedef unsigned short u16x8 __attribute__((ext_vector_type(8)));

#define BM 128
#define BN 128
#define BK 64
#define THREADS 256

static __device__ __forceinline__ u16 f2bf(float f) {
    __hip_bfloat16 h = __float2bfloat16(f);
    return __builtin_bit_cast(u16, h);
}

// ---------------- i8 precompute kernels ----------------

__global__ void rowstat_kernel(const float* __restrict__ x, float* __restrict__ sx,
                               float* __restrict__ rsx, int K) {
    const int m = blockIdx.x;
    const int l = threadIdx.x;  // 64
    const float4* p = (const float4*)(x + (size_t)m * K);
    float mx = 0.f;
    for (int i = l; i < (K >> 2); i += 64) {
        const float4 v = p[i];
        mx = fmaxf(mx, fmaxf(fmaxf(fabsf(v.x), fabsf(v.y)),
                             fmaxf(fabsf(v.z), fabsf(v.w))));
    }
    #pragma unroll
    for (int o = 32; o; o >>= 1) mx = fmaxf(mx, __shfl_xor(mx, o));
    if (l == 0) {
        mx = fmaxf(mx, 1e-20f);
        sx[m]  = mx * (1.f / 127.f);
        rsx[m] = 127.f / mx;
    }
}

__global__ void quantX_kernel(const float* __restrict__ x, const float* __restrict__ rsx,
                              char* __restrict__ xq, int kshift, size_t n16) {
    size_t i = (size_t)blockIdx.x * blockDim.x + threadIdx.x;
    if (i >= n16) return;
    const int m = (int)((i * 16) >> kshift);
    const float r = rsx[m];
    const float4* px = (const float4*)(x + i * 16);
    int out[4];
    #pragma unroll
    for (int w = 0; w < 4; ++w) {
        const float4 v = px[w];
        const int b0 = __float2int_rn(v.x * r) & 0xFF;
        const int b1 = __float2int_rn(v.y * r) & 0xFF;
        const int b2 = __float2int_rn(v.z * r) & 0xFF;
        const int b3 = __float2int_rn(v.w * r) & 0xFF;
        out[w] = b0 | (b1 << 8) | (b2 << 16) | (b3 << 24);
    }
    *(int4*)(xq + i * 16) = make_int4(out[0], out[1], out[2], out[3]);
}

// thread = (n, 16-k chunk): 4 packed words -> 16 i8; also writes sw once/group
__global__ void quantW_kernel(const int* __restrict__ Wp, const float* __restrict__ Ws,
                              const float* __restrict__ Wb, char* __restrict__ wq,
                              float* __restrict__ sw, int K, int G, int gshift,
                              int kcshift, int gkmask16, size_t nthr) {
    size_t t = (size_t)blockIdx.x * blockDim.x + threadIdx.x;
    if (t >= nthr) return;
    const int n  = (int)(t >> kcshift);
    const int kc = (int)(t & ((1u << kcshift) - 1));
    const int g  = (kc << 4) >> gshift;
    const float s = Ws[(size_t)n * G + g];
    const float b = Wb[(size_t)n * G + g];
    float maxv = fmaxf(fabsf(b), fabsf(fmaf(15.f, s, b)));
    maxv = fmaxf(maxv, 1e-20f);
    const float rsw = 127.f / maxv;
    if ((kc & gkmask16) == 0) sw[(size_t)n * G + g] = maxv * (1.f / 127.f);
    const int4 wv = *(const int4*)(Wp + (size_t)n * (K >> 2) + ((size_t)kc << 2));
    const int wds[4] = {wv.x, wv.y, wv.z, wv.w};
    int out[4];
    #pragma unroll
    for (int w = 0; w < 4; ++w) {
        int o = 0;
        #pragma unroll
        for (int j = 0; j < 4; ++j) {
            const float v = fmaf((float)((wds[w] >> (4 * j)) & 0xF), s, b);
            o |= (__float2int_rn(v * rsw) & 0xFF) << (8 * j);
        }
        out[w] = o;
    }
    *(int4*)(wq + t * 16) = make_int4(out[0], out[1], out[2], out[3]);
}

// ---------------- i8 GEMM: 128x256 block, 8 waves of 64x64, BK=128 ----------------

__global__ __launch_bounds__(512, 2)
void gql_gemm_i8(const char* __restrict__ xq,   // [M][K] i8
                 const char* __restrict__ wq,   // [N][K] i8
                 const float* __restrict__ sw,  // [N][G]
                 const float* __restrict__ sx,  // [M]
                 const float* __restrict__ Bias,
                 float* __restrict__ Out,       // [M][N] f32
                 int M, int N, int K, int G, int tshift)
{
    __shared__ __align__(16) char sA[2][128 * 128];  // 16 KB each
    __shared__ __align__(16) char sB[2][256 * 128];  // 32 KB each -> 96 KB

    const int tid  = threadIdx.x;
    const int lane = tid & 63;
    const int wid  = tid >> 6;     // 0..7
    const int wm   = wid >> 2;     // 0..1 -> rows wm*64 (of 128)
    const int wn   = wid & 3;      // 0..3 -> cols wn*64 (of 256)

    const int nwg = gridDim.x;
    int wg = blockIdx.x;
    if ((nwg & 7) == 0) wg = (wg & 7) * (nwg >> 3) + (wg >> 3);
    const int nt = N / 256;
    const int m0 = (wg / nt) * 128;
    const int n0 = (wg % nt) * 256;

    // staging: inst = 8 rows x 128B (i8 row = 128B, same geometry as bf16 BK64)
    const int st_row = lane >> 3;                        // 0..7
    const int st_g   = ((lane & 7) ^ (lane >> 3)) << 4;  // pre-swizzled byte off

    const int tmask = (1 << tshift) - 1;

    i32x16 acc[2][2] = {};
    float y[2][2][16] = {};

    const int NT = K >> 7;  // BK=128

    auto stage = [&](int t, int buf) {
        const size_t k0 = (size_t)t << 7;
        #pragma unroll
        for (int i = 0; i < 2; ++i) {
            const int r = wid * 16 + i * 8 + st_row;
            const char* src = xq + (size_t)(m0 + r) * K + k0 + st_g;
            __builtin_amdgcn_global_load_lds(
                (const __attribute__((address_space(1))) void*)src,
                (__attribute__((address_space(3))) void*)&sA[buf][(wid * 16 + i * 8) * 128],
                16, 0, 0);
        }
        #pragma unroll
        for (int i = 0; i < 4; ++i) {
            const int r = wid * 32 + i * 8 + st_row;
            const char* src = wq + (size_t)(n0 + r) * K + k0 + st_g;
            __builtin_amdgcn_global_load_lds(
                (const __attribute__((address_space(1))) void*)src,
                (__attribute__((address_space(3))) void*)&sB[buf][(wid * 32 + i * 8) * 128],
                16, 0, 0);
        }
    };

    auto compute = [&](int buf) {
        #pragma unroll
        for (int kk = 0; kk < 4; ++kk) {
            i32x4 af[2], bfr[2];
            #pragma unroll
            for (int mi = 0; mi < 2; ++mi) {
                const int row = wm * 64 + mi * 32 + (lane & 31);
                const int gr  = (kk * 2 + (lane >> 5)) ^ (row & 7);
                af[mi] = *(const i32x4*)&sA[buf][row * 128 + gr * 16];
            }
            #pragma unroll
            for (int nj = 0; nj < 2; ++nj) {
                const int row = wn * 64 + nj * 32 + (lane & 31);
                const int gr  = (kk * 2 + (lane >> 5)) ^ (row & 7);
                bfr[nj] = *(const i32x4*)&sB[buf][row * 128 + gr * 16];
            }
            __builtin_amdgcn_s_setprio(1);
            #pragma unroll
            for (int mi = 0; mi < 2; ++mi)
                #pragma unroll
                for (int nj = 0; nj < 2; ++nj)
                    acc[mi][nj] = __builtin_amdgcn_mfma_i32_32x32x32_i8(
                        af[mi], bfr[nj], acc[mi][nj], 0, 0, 0);
            __builtin_amdgcn_s_setprio(0);
        }
    };

    auto rescale = [&](int g) {
        #pragma unroll
        for (int nj = 0; nj < 2; ++nj) {
            const int col = n0 + wn * 64 + nj * 32 + (lane & 31);
            const float s = sw[(size_t)col * G + g];
            #pragma unroll
            for (int mi = 0; mi < 2; ++mi) {
                #pragma unroll
                for (int r = 0; r < 16; ++r) {
                    y[mi][nj][r] = fmaf(s, (float)acc[mi][nj][r], y[mi][nj][r]);
                    acc[mi][nj][r] = 0;
                }
            }
        }
    };

    stage(0, 0);
    int cur = 0;
    for (int t = 0; t < NT - 1; ++t) {
        stage(t + 1, cur ^ 1);                 // overwrites buf consumed at t-1
        __builtin_amdgcn_sched_barrier(0);
        asm volatile("s_waitcnt vmcnt(6)" ::: "memory");  // tile t landed
        __builtin_amdgcn_s_barrier();
        asm volatile("" ::: "memory");
        compute(cur);
        if (((t + 1) & tmask) == 0) rescale(t >> tshift);
        __builtin_amdgcn_sched_barrier(0);
        asm volatile("" ::: "memory");
        __builtin_amdgcn_s_barrier();          // readers done before overwrite
        asm volatile("" ::: "memory");
        cur ^= 1;
    }
    asm volatile("s_waitcnt vmcnt(0)" ::: "memory");
    __builtin_amdgcn_s_barrier();
    asm volatile("" ::: "memory");
    compute(cur);
    rescale((NT - 1) >> tshift);

    // epilogue: C-layout 32x32: col = lane&31, row = (r&3)+8*(r>>2)+4*(lane>>5)
    float bv[2];
    #pragma unroll
    for (int nj = 0; nj < 2; ++nj)
        bv[nj] = Bias[n0 + wn * 64 + nj * 32 + (lane & 31)];
    #pragma unroll
    for (int mi = 0; mi < 2; ++mi) {
        #pragma unroll
        for (int r = 0; r < 16; ++r) {
            const int row = m0 + wm * 64 + mi * 32 + (r & 3) + 8 * (r >> 2) + 4 * (lane >> 5);
            const float sxv = sx[row];
            #pragma unroll
            for (int nj = 0; nj < 2; ++nj) {
                const int col = n0 + wn * 64 + nj * 32 + (lane & 31);
                Out[(size_t)row * N + col] = fmaf(sxv, y[mi][nj][r], bv[nj]);
            }
        }
    }
}

// ---------------- bf16 predecode kernels (fallback path) ----------------

__global__ void cvtA_kernel(const float* __restrict__ A, u16* __restrict__ wsA,
                            size_t n8) {
    size_t i = (size_t)blockIdx.x * blockDim.x + threadIdx.x;
    if (i >= n8) return;
    const float4 v0 = *(const float4*)(A + i * 8);
    const float4 v1 = *(const float4*)(A + i * 8 + 4);
    u16x8 h;
    h[0] = f2bf(v0.x); h[1] = f2bf(v0.y); h[2] = f2bf(v0.z); h[3] = f2bf(v0.w);
    h[4] = f2bf(v1.x); h[5] = f2bf(v1.y); h[6] = f2bf(v1.z); h[7] = f2bf(v1.w);
    *(u16x8*)(wsA + i * 8) = h;
}

__global__ void deqW_kernel(const int* __restrict__ Wp, const float* __restrict__ Ws,
                            const float* __restrict__ Wb, u16* __restrict__ wsW,
                            int K, int G, int gshift, int kgshift, size_t n8) {
    size_t t = (size_t)blockIdx.x * blockDim.x + threadIdx.x;
    if (t >= n8) return;
    const int n  = (int)(t >> kgshift);
    const int kg = (int)(t & ((1u << kgshift) - 1));
    const int k  = kg << 3;
    const int g  = k >> gshift;
    const float s = Ws[n * G + g];
    const float b = Wb[n * G + g];
    const int2 w2 = *(const int2*)(Wp + (size_t)n * (K >> 2) + (k >> 2));
    u16x8 h;
    #pragma unroll
    for (int j = 0; j < 4; ++j)
        h[j]     = f2bf(fmaf((float)((w2.x >> (4 * j)) & 0xF), s, b));
    #pragma unroll
    for (int j = 0; j < 4; ++j)
        h[4 + j] = f2bf(fmaf((float)((w2.y >> (4 * j)) & 0xF), s, b));
    *(u16x8*)(wsW + ((size_t)n << (kgshift + 3)) + k) = h;
}

__global__ __launch_bounds__(THREADS, 2)
void gql_gemm_pre(const u16* __restrict__ wsA,
                  const u16* __restrict__ wsW,
                  const float* __restrict__ Bias,
                  float* __restrict__ Out,
                  int M, int N, int K)
{
    __shared__ __align__(16) u16 sA[BM * BK];
    __shared__ __align__(16) u16 sB[BN * BK];

    const int tid  = threadIdx.x;
    const int lane = tid & 63;
    const int wid  = tid >> 6;

    const int nwg = gridDim.x;
    int wg = blockIdx.x;
    if ((nwg & 7) == 0) wg = (wg & 7) * (nwg >> 3) + (wg >> 3);
    const int nt     = N / BN;
    const int m0 = (wg / nt) * BM;
    const int n0 = (wg % nt) * BN;

    const int st_r  = (lane >> 3);
    const int st_g  = lane & 7;

    const int wr = (wid >> 1) << 6;
    const int wc = (wid & 1) << 6;
    const int fr = lane & 15;
    const int fq = lane >> 4;

    f32x4 acc[4][4] = {};

    for (int k0 = 0; k0 < K; k0 += BK) {
        __syncthreads();

        #pragma unroll
        for (int i = 0; i < 4; ++i) {
            const int r = wid * 32 + i * 8 + st_r;
            const int gsrc = (st_g ^ (r & 7)) << 3;
            const u16* srcA = wsA + (size_t)(m0 + r) * K + k0 + gsrc;
            const u16* srcB = wsW + (size_t)(n0 + r) * K + k0 + gsrc;
            __builtin_amdgcn_global_load_lds(
                (const __attribute__((address_space(1))) void*)srcA,
                (__attribute__((address_space(3))) void*)&sA[(wid * 32 + i * 8) * BK],
                16, 0, 0);
            __builtin_amdgcn_global_load_lds(
                (const __attribute__((address_space(1))) void*)srcB,
                (__attribute__((address_space(3))) void*)&sB[(wid * 32 + i * 8) * BK],
                16, 0, 0);
        }

        __syncthreads();

        #pragma unroll
        for (int sub = 0; sub < 2; ++sub) {
            const int kch = (sub << 2) + fq;
            bf16x8 af[4], bfg[4];
            #pragma unroll
            for (int i = 0; i < 4; ++i) {
                const int row = wr + i * 16 + fr;
                af[i] = *(const bf16x8*)((const char*)sA + row * (BK * 2)
                                         + (((kch ^ (row & 7)) << 4)));
            }
            #pragma unroll
            for (int j = 0; j < 4; ++j) {
                const int row = wc + j * 16 + fr;
                bfg[j] = *(const bf16x8*)((const char*)sB + row * (BK * 2)
                                          + (((kch ^ (row & 7)) << 4)));
            }
            #pragma unroll
            for (int i = 0; i < 4; ++i)
                #pragma unroll
                for (int j = 0; j < 4; ++j)
                    acc[i][j] = __builtin_amdgcn_mfma_f32_16x16x32_bf16(
                        af[i], bfg[j], acc[i][j], 0, 0, 0);
        }
    }

    #pragma unroll
    for (int j = 0; j < 4; ++j) {
        const int n = n0 + wc + j * 16 + fr;
        const float bvv = Bias[n];
        #pragma unroll
        for (int i = 0; i < 4; ++i) {
            const int mb = m0 + wr + i * 16 + (fq << 2);
            #pragma unroll
            for (int r = 0; r < 4; ++r)
                Out[(size_t)(mb + r) * N + n] = acc[i][j][r] + bvv;
        }
    }
}

// ---------------- round-1 fused fallback ----------------

__global__ __launch_bounds__(THREADS, 2)
void gql_gemm(const float* __restrict__ A,
              const int* __restrict__ Wp,
              const float* __restrict__ Ws,
              const float* __restrict__ Wb,
              const float* __restrict__ Bias,
              float* __restrict__ Out,
              int M, int N, int K, int G, int gshift)
{
    __shared__ __align__(16) u16 sA[BM * BK];
    __shared__ __align__(16) u16 sB[BN * BK];

    const int tid  = threadIdx.x;
    const int lane = tid & 63;
    const int wid  = tid >> 6;

    const int nwg = gridDim.x;
    int wg = blockIdx.x;
    if ((nwg & 7) == 0) wg = (wg & 7) * (nwg >> 3) + (wg >> 3);
    const int nt     = N / BN;
    const int m0 = (wg / nt) * BM;
    const int n0 = (wg % nt) * BN;

    const int wpr = K >> 2;

    const int a_r = tid >> 4;
    const int a_c = (tid & 15) << 2;
    const int b_r = tid >> 3;
    const int b_w = (tid & 7) << 1;

    const int wr = (wid >> 1) << 6;
    const int wc = (wid & 1) << 6;
    const int fr = lane & 15;
    const int fq = lane >> 4;

    f32x4 acc[4][4] = {};

    for (int k0 = 0; k0 < K; k0 += BK) {
        __syncthreads();

        #pragma unroll
        for (int it = 0; it < 8; ++it) {
            const int row = it * 16 + a_r;
            const float4 v = *(const float4*)(A + (size_t)(m0 + row) * K + (k0 + a_c));
            u16x4 h;
            h[0] = f2bf(v.x); h[1] = f2bf(v.y); h[2] = f2bf(v.z); h[3] = f2bf(v.w);
            const int byte = (a_c << 1) ^ ((row & 7) << 4);
            *(u16x4*)((char*)sA + row * (BK * 2) + byte) = h;
        }

        const int g = k0 >> gshift;
        #pragma unroll
        for (int it = 0; it < 4; ++it) {
            const int row = it * 32 + b_r;
            const int gn  = n0 + row;
            const int2 w2 = *(const int2*)(Wp + (size_t)gn * wpr + (k0 >> 2) + b_w);
            const float s = Ws[gn * G + g];
            const float b = Wb[gn * G + g];
            u16x8 h;
            #pragma unroll
            for (int j = 0; j < 4; ++j)
                h[j]     = f2bf(fmaf((float)((w2.x >> (4 * j)) & 0xF), s, b));
            #pragma unroll
            for (int j = 0; j < 4; ++j)
                h[4 + j] = f2bf(fmaf((float)((w2.y >> (4 * j)) & 0xF), s, b));
            const int byte = (b_w << 3) ^ ((row & 7) << 4);
            *(u16x8*)((char*)sB + row * (BK * 2) + byte) = h;
        }

        __syncthreads();

        #pragma unroll
        for (int sub = 0; sub < 2; ++sub) {
            const int kch = (sub << 2) + fq;
            bf16x8 af[4], bfg[4];
            #pragma unroll
            for (int i = 0; i < 4; ++i) {
                const int row = wr + i * 16 + fr;
                af[i] = *(const bf16x8*)((const char*)sA + row * (BK * 2)
                                         + ((kch << 4) ^ ((row & 7) << 4)));
            }
            #pragma unroll
            for (int j = 0; j < 4; ++j) {
                const int row = wc + j * 16 + fr;
                bfg[j] = *(const bf16x8*)((const char*)sB + row * (BK * 2)
                                          + ((kch << 4) ^ ((row & 7) << 4)));
            }
            #pragma unroll
            for (int i = 0; i < 4; ++i)
                #pragma unroll
                for (int j = 0; j < 4; ++j)
                    acc[i][j] = __builtin_amdgcn_mfma_f32_16x16x32_bf16(
                        af[i], bfg[j], acc[i][j], 0, 0, 0);
        }
    }

    #pragma unroll
    for (int j = 0; j < 4; ++j) {
        const int n = n0 + wc + j * 16 + fr;
        const float bvv = Bias[n];
        #pragma unroll
        for (int i = 0; i < 4; ++i) {
            const int mb = m0 + wr + i * 16 + (fq << 2);
            #pragma unroll
            for (int r = 0; r < 4; ++r)
                Out[(size_t)(mb + r) * N + n] = acc[i][j][r] + bvv;
        }
    }
}

extern "C" void kernel_launch(void* const* d_in, const int* in_sizes, int n_in,
                              void* d_out, int out_size, void* d_ws, size_t ws_size,
                              hipStream_t stream) {
    const float* A    = (const float*)d_in[0];
    const int*   Wp   = (const int*)d_in[1];
    const float* Ws   = (const float*)d_in[2];
    const float* Wb   = (const float*)d_in[3];
    const float* Bias = (const float*)d_in[4];
    float* Out = (float*)d_out;

    const int OUT  = in_sizes[4];
    const int OG   = in_sizes[2];          // OUT * G
    const int G    = OG / OUT;             // 16
    const int cols = in_sizes[1] / OG;     // 64
    const int IN   = G * cols * 4;         // 4096
    const int M    = in_sizes[0] / IN;     // 4096

    const int gk = IN / G;                 // 256
    int gshift = 0;
    while ((1 << gshift) < gk) ++gshift;   // 8

    int kshift = 0;
    while ((1 << kshift) < IN) ++kshift;   // 12

    const size_t needXq = (size_t)M * IN;
    const size_t needWq = (size_t)OUT * IN;
    const size_t needSc = (size_t)M * 8 + (size_t)OUT * G * 4;
    const size_t needI8 = needXq + needWq + needSc;

    const bool kpow2  = ((IN & (IN - 1)) == 0);
    const bool gkpow2 = ((1 << gshift) == gk);

    if (ws_size >= needI8 && kpow2 && gkpow2 && gk >= 128 && (gk % 128) == 0 &&
        (M % 128) == 0 && (OUT % 256) == 0 && IN >= 256) {
        char*  xq  = (char*)d_ws;
        char*  wq  = (char*)d_ws + needXq;
        float* sx  = (float*)((char*)d_ws + needXq + needWq);
        float* rsx = sx + M;
        float* sw  = rsx + M;

        rowstat_kernel<<<M, 64, 0, stream>>>(A, sx, rsx, IN);

        const size_t n16 = (size_t)M * IN / 16;
        quantX_kernel<<<(unsigned)((n16 + 255) / 256), 256, 0, stream>>>(
            A, rsx, xq, kshift, n16);

        const int kcshift = kshift - 4;                 // log2(K/16)
        const int gkmask16 = (gk >> 4) - 1;
        const size_t nthr = (size_t)OUT * (IN >> 4);
        quantW_kernel<<<(unsigned)((nthr + 255) / 256), 256, 0, stream>>>(
            Wp, Ws, Wb, wq, sw, IN, G, gshift, kcshift, gkmask16, nthr);

        int tshift = 0;                                  // log2(gk/128)
        while ((128 << tshift) < gk) ++tshift;           // gk=256 -> 1

        dim3 grid((M / 128) * (OUT / 256));
        gql_gemm_i8<<<grid, 512, 0, stream>>>(xq, wq, sw, sx, Bias, Out,
                                              M, OUT, IN, G, tshift);
        return;
    }

    const size_t needA = (size_t)M * IN * 2;
    const size_t needW = (size_t)OUT * IN * 2;

    if (ws_size >= needA + needW && (IN & 7) == 0 &&
        (M % 128) == 0 && (OUT % 128) == 0 && (IN % 64) == 0) {
        u16* wsA = (u16*)d_ws;
        u16* wsW = (u16*)((char*)d_ws + needA);

        const size_t nA8 = (size_t)M * IN / 8;
        cvtA_kernel<<<(unsigned)((nA8 + 255) / 256), 256, 0, stream>>>(A, wsA, nA8);

        int kgshift = 0;
        while ((1 << kgshift) < (IN >> 3)) ++kgshift;
        const size_t nW8 = (size_t)OUT * IN / 8;
        deqW_kernel<<<(unsigned)((nW8 + 255) / 256), 256, 0, stream>>>(
            Wp, Ws, Wb, wsW, IN, G, gshift, kgshift, nW8);

        dim3 grid((M / BM) * (OUT / BN));
        gql_gemm_pre<<<grid, THREADS, 0, stream>>>(wsA, wsW, Bias, Out, M, OUT, IN);
    } else {
        dim3 grid((M / BM) * (OUT / BN));
        gql_gemm<<<grid, THREADS, 0, stream>>>(A, Wp, Ws, Wb, Bias, Out,
                                               M, OUT, IN, G, gshift);
    }
}

// Round 7
// 361.103 us; speedup vs baseline: 2.1259x; 1.4479x over previous
//
#include <hip/hip_runtime.h>
#include <hip/hip_bf16.h>

// GroupQuantLinear: y[m,n] = sum_k x[m,k]*(q[n,k]*s[n,g]+b[n,g]) + bias[n]
// M=4096, N=16384, K=4096, G=16.
//
// Round 7: i8 path, v2.
//  - LDS reads via u16x8 (proven ds_read_b128 idiom, 0 conflicts r2-r5),
//    bit_cast to i32x4 for the MFMA. (r6 used i32x4 casts off char*: 3.4e7
//    bank-conflict cycles -> hypothesis: compiler split them into b64s.)
//  - Per-ROW weight scale swr[n] (not per-group): i32 acc over full K=4096
//    is exact (max 6.6e7 < 2^31) -> no f32 y accumulator, no rescale pass.
//  - Bigger wave tile 128x64 (block 256x256, 8 waves, BK=128): MAC per
//    LDS-byte 32 -> 42.7, ceiling ~50% MfmaUtil.
//  - r3-validated loop: dbuf, stage t+1, counted vmcnt(8), raw barriers.
// Fallbacks: r2 bf16-predecode 128^2 kernel; r1 fused kernel.

typedef short bf16x8 __attribute__((ext_vector_type(8)));
typedef float f32x4 __attribute__((ext_vector_type(4)));
typedef int i32x4 __attribute__((ext_vector_type(4)));
typedef int i32x16 __attribute__((ext_vector_type(16)));
typedef unsigned short u16;
typedef unsigned short u16x8 __attribute__((ext_vector_type(8)));

#define BM 128
#define BN 128
#define BK 64
#define THREADS 256

static __device__ __forceinline__ u16 f2bf(float f) {
    __hip_bfloat16 h = __float2bfloat16(f);
    return __builtin_bit_cast(u16, h);
}

// ---------------- i8 precompute kernels ----------------

__global__ void rowstat_kernel(const float* __restrict__ x, float* __restrict__ sx,
                               float* __restrict__ rsx, int K) {
    const int m = blockIdx.x;
    const int l = threadIdx.x;  // 64
    const float4* p = (const float4*)(x + (size_t)m * K);
    float mx = 0.f;
    for (int i = l; i < (K >> 2); i += 64) {
        const float4 v = p[i];
        mx = fmaxf(mx, fmaxf(fmaxf(fabsf(v.x), fabsf(v.y)),
                             fmaxf(fabsf(v.z), fabsf(v.w))));
    }
    #pragma unroll
    for (int o = 32; o; o >>= 1) mx = fmaxf(mx, __shfl_xor(mx, o));
    if (l == 0) {
        mx = fmaxf(mx, 1e-20f);
        sx[m]  = mx * (1.f / 127.f);
        rsx[m] = 127.f / mx;
    }
}

__global__ void quantX_kernel(const float* __restrict__ x, const float* __restrict__ rsx,
                              char* __restrict__ xq, int kshift, size_t n16) {
    size_t i = (size_t)blockIdx.x * blockDim.x + threadIdx.x;
    if (i >= n16) return;
    const int m = (int)((i * 16) >> kshift);
    const float r = rsx[m];
    const float4* px = (const float4*)(x + i * 16);
    int out[4];
    #pragma unroll
    for (int w = 0; w < 4; ++w) {
        const float4 v = px[w];
        const int b0 = __float2int_rn(v.x * r) & 0xFF;
        const int b1 = __float2int_rn(v.y * r) & 0xFF;
        const int b2 = __float2int_rn(v.z * r) & 0xFF;
        const int b3 = __float2int_rn(v.w * r) & 0xFF;
        out[w] = b0 | (b1 << 8) | (b2 << 16) | (b3 << 24);
    }
    *(int4*)(xq + i * 16) = make_int4(out[0], out[1], out[2], out[3]);
}

// per-row W scale: swr[n] = max over groups of max(|b|, |15s+b|) / 127
__global__ void rowscaleW_kernel(const float* __restrict__ Ws,
                                 const float* __restrict__ Wb,
                                 float* __restrict__ swr, float* __restrict__ rswr,
                                 int G, int N) {
    const int n = blockIdx.x * blockDim.x + threadIdx.x;
    if (n >= N) return;
    float mx = 1e-20f;
    for (int g = 0; g < G; ++g) {
        const float s = Ws[(size_t)n * G + g];
        const float b = Wb[(size_t)n * G + g];
        mx = fmaxf(mx, fmaxf(fabsf(b), fabsf(fmaf(15.f, s, b))));
    }
    swr[n]  = mx * (1.f / 127.f);
    rswr[n] = 127.f / mx;
}

// thread = (n, 16-k chunk): 4 packed words -> 16 i8 with per-row scale
__global__ void quantW_row_kernel(const int* __restrict__ Wp, const float* __restrict__ Ws,
                                  const float* __restrict__ Wb, const float* __restrict__ rswr,
                                  char* __restrict__ wq, int K, int G, int gshift,
                                  int kcshift, size_t nthr) {
    size_t t = (size_t)blockIdx.x * blockDim.x + threadIdx.x;
    if (t >= nthr) return;
    const int n  = (int)(t >> kcshift);
    const int kc = (int)(t & ((1u << kcshift) - 1));
    const int g  = (kc << 4) >> gshift;
    const float s = Ws[(size_t)n * G + g];
    const float b = Wb[(size_t)n * G + g];
    const float rs = rswr[n];
    const int4 wv = *(const int4*)(Wp + (size_t)n * (K >> 2) + ((size_t)kc << 2));
    const int wds[4] = {wv.x, wv.y, wv.z, wv.w};
    int out[4];
    #pragma unroll
    for (int w = 0; w < 4; ++w) {
        int o = 0;
        #pragma unroll
        for (int j = 0; j < 4; ++j) {
            const float v = fmaf((float)((wds[w] >> (4 * j)) & 0xF), s, b);
            o |= (__float2int_rn(v * rs) & 0xFF) << (8 * j);
        }
        out[w] = o;
    }
    *(int4*)(wq + t * 16) = make_int4(out[0], out[1], out[2], out[3]);
}

// ------- i8 GEMM: 256x256 block, 8 waves of 128x64, BK=128, full-K i32 acc -------

__global__ __launch_bounds__(512, 2)
void gql_gemm_i8r(const char* __restrict__ xq,   // [M][K] i8
                  const char* __restrict__ wq,   // [N][K] i8
                  const float* __restrict__ swr, // [N]
                  const float* __restrict__ sx,  // [M]
                  const float* __restrict__ Bias,
                  float* __restrict__ Out,       // [M][N] f32
                  int M, int N, int K)
{
    __shared__ __align__(16) char sA[2][256 * 128];  // 32 KB each
    __shared__ __align__(16) char sB[2][256 * 128];  // 32 KB each -> 128 KB

    const int tid  = threadIdx.x;
    const int lane = tid & 63;
    const int wid  = tid >> 6;     // 0..7
    const int wm   = wid >> 2;     // 0..1 -> rows wm*128
    const int wn   = wid & 3;      // 0..3 -> cols wn*64

    const int nwg = gridDim.x;
    int wg = blockIdx.x;
    if ((nwg & 7) == 0) wg = (wg & 7) * (nwg >> 3) + (wg >> 3);
    const int nt = N / 256;
    const int m0 = (wg / nt) * 256;
    const int n0 = (wg % nt) * 256;

    // staging: inst = 8 rows x 128B, linear LDS dest, pre-swizzled source
    // (granule ^= row&7) -> swizzled read conflict-free. r2-r6 validated.
    const int st_row = lane >> 3;                        // 0..7
    const int st_g   = ((lane & 7) ^ (lane >> 3)) << 4;  // byte offset

    i32x16 acc[4][2] = {};

    const int NT = K >> 7;  // BK=128

    auto stage = [&](int t, int buf) {
        const size_t k0 = (size_t)t << 7;
        #pragma unroll
        for (int i = 0; i < 4; ++i) {
            const int r = wid * 32 + i * 8 + st_row;
            const char* srcA = xq + (size_t)(m0 + r) * K + k0 + st_g;
            __builtin_amdgcn_global_load_lds(
                (const __attribute__((address_space(1))) void*)srcA,
                (__attribute__((address_space(3))) void*)&sA[buf][(wid * 32 + i * 8) * 128],
                16, 0, 0);
            const char* srcB = wq + (size_t)(n0 + r) * K + k0 + st_g;
            __builtin_amdgcn_global_load_lds(
                (const __attribute__((address_space(1))) void*)srcB,
                (__attribute__((address_space(3))) void*)&sB[buf][(wid * 32 + i * 8) * 128],
                16, 0, 0);
        }
    };

    // LDS read via u16x8 (emits ds_read_b128; r2-r5 measured 0 conflicts),
    // bit_cast to i32x4 for the MFMA operands.
    auto ldsrd = [&](const char* base, int row, int gr) -> i32x4 {
        const u16x8 raw = *(const u16x8*)(base + row * 128 + gr * 16);
        return __builtin_bit_cast(i32x4, raw);
    };

    auto compute = [&](int buf) {
        #pragma unroll
        for (int kk = 0; kk < 4; ++kk) {
            i32x4 af[4], bfr[2];
            #pragma unroll
            for (int mi = 0; mi < 4; ++mi) {
                const int row = wm * 128 + mi * 32 + (lane & 31);
                const int gr  = (kk * 2 + (lane >> 5)) ^ (row & 7);
                af[mi] = ldsrd(&sA[buf][0], row, gr);
            }
            #pragma unroll
            for (int nj = 0; nj < 2; ++nj) {
                const int row = wn * 64 + nj * 32 + (lane & 31);
                const int gr  = (kk * 2 + (lane >> 5)) ^ (row & 7);
                bfr[nj] = ldsrd(&sB[buf][0], row, gr);
            }
            __builtin_amdgcn_s_setprio(1);
            #pragma unroll
            for (int mi = 0; mi < 4; ++mi)
                #pragma unroll
                for (int nj = 0; nj < 2; ++nj)
                    acc[mi][nj] = __builtin_amdgcn_mfma_i32_32x32x32_i8(
                        af[mi], bfr[nj], acc[mi][nj], 0, 0, 0);
            __builtin_amdgcn_s_setprio(0);
        }
    };

    stage(0, 0);
    int cur = 0;
    for (int t = 0; t < NT - 1; ++t) {
        stage(t + 1, cur ^ 1);                 // overwrites buf consumed at t-1
        __builtin_amdgcn_sched_barrier(0);
        asm volatile("s_waitcnt vmcnt(8)" ::: "memory");  // tile t landed
        __builtin_amdgcn_s_barrier();
        asm volatile("" ::: "memory");
        compute(cur);
        __builtin_amdgcn_sched_barrier(0);
        asm volatile("" ::: "memory");
        __builtin_amdgcn_s_barrier();          // readers done before overwrite
        asm volatile("" ::: "memory");
        cur ^= 1;
    }
    asm volatile("s_waitcnt vmcnt(0)" ::: "memory");
    __builtin_amdgcn_s_barrier();
    asm volatile("" ::: "memory");
    compute(cur);

    // epilogue: 32x32 C-layout (r6-validated): col = lane&31,
    // row = (r&3) + 8*(r>>2) + 4*(lane>>5). Out = sx[m]*swr[n]*acc + bias[n].
    float bv[2], sv[2];
    #pragma unroll
    for (int nj = 0; nj < 2; ++nj) {
        const int col = n0 + wn * 64 + nj * 32 + (lane & 31);
        bv[nj] = Bias[col];
        sv[nj] = swr[col];
    }
    #pragma unroll
    for (int mi = 0; mi < 4; ++mi) {
        #pragma unroll
        for (int r = 0; r < 16; ++r) {
            const int row = m0 + wm * 128 + mi * 32 + (r & 3) + 8 * (r >> 2) + 4 * (lane >> 5);
            const float sxv = sx[row];
            #pragma unroll
            for (int nj = 0; nj < 2; ++nj) {
                const int col = n0 + wn * 64 + nj * 32 + (lane & 31);
                Out[(size_t)row * N + col] =
                    fmaf(sxv * sv[nj], (float)acc[mi][nj][r], bv[nj]);
            }
        }
    }
}

// ---------------- bf16 predecode kernels (fallback path) ----------------

__global__ void cvtA_kernel(const float* __restrict__ A, u16* __restrict__ wsA,
                            size_t n8) {
    size_t i = (size_t)blockIdx.x * blockDim.x + threadIdx.x;
    if (i >= n8) return;
    const float4 v0 = *(const float4*)(A + i * 8);
    const float4 v1 = *(const float4*)(A + i * 8 + 4);
    u16x8 h;
    h[0] = f2bf(v0.x); h[1] = f2bf(v0.y); h[2] = f2bf(v0.z); h[3] = f2bf(v0.w);
    h[4] = f2bf(v1.x); h[5] = f2bf(v1.y); h[6] = f2bf(v1.z); h[7] = f2bf(v1.w);
    *(u16x8*)(wsA + i * 8) = h;
}

__global__ void deqW_kernel(const int* __restrict__ Wp, const float* __restrict__ Ws,
                            const float* __restrict__ Wb, u16* __restrict__ wsW,
                            int K, int G, int gshift, int kgshift, size_t n8) {
    size_t t = (size_t)blockIdx.x * blockDim.x + threadIdx.x;
    if (t >= n8) return;
    const int n  = (int)(t >> kgshift);
    const int kg = (int)(t & ((1u << kgshift) - 1));
    const int k  = kg << 3;
    const int g  = k >> gshift;
    const float s = Ws[n * G + g];
    const float b = Wb[n * G + g];
    const int2 w2 = *(const int2*)(Wp + (size_t)n * (K >> 2) + (k >> 2));
    u16x8 h;
    #pragma unroll
    for (int j = 0; j < 4; ++j)
        h[j]     = f2bf(fmaf((float)((w2.x >> (4 * j)) & 0xF), s, b));
    #pragma unroll
    for (int j = 0; j < 4; ++j)
        h[4 + j] = f2bf(fmaf((float)((w2.y >> (4 * j)) & 0xF), s, b));
    *(u16x8*)(wsW + ((size_t)n << (kgshift + 3)) + k) = h;
}

__global__ __launch_bounds__(THREADS, 2)
void gql_gemm_pre(const u16* __restrict__ wsA,
                  const u16* __restrict__ wsW,
                  const float* __restrict__ Bias,
                  float* __restrict__ Out,
                  int M, int N, int K)
{
    __shared__ __align__(16) u16 sA[BM * BK];
    __shared__ __align__(16) u16 sB[BN * BK];

    const int tid  = threadIdx.x;
    const int lane = tid & 63;
    const int wid  = tid >> 6;

    const int nwg = gridDim.x;
    int wg = blockIdx.x;
    if ((nwg & 7) == 0) wg = (wg & 7) * (nwg >> 3) + (wg >> 3);
    const int nt     = N / BN;
    const int m0 = (wg / nt) * BM;
    const int n0 = (wg % nt) * BN;

    const int st_r  = (lane >> 3);
    const int st_g  = lane & 7;

    const int wr = (wid >> 1) << 6;
    const int wc = (wid & 1) << 6;
    const int fr = lane & 15;
    const int fq = lane >> 4;

    f32x4 acc[4][4] = {};

    for (int k0 = 0; k0 < K; k0 += BK) {
        __syncthreads();

        #pragma unroll
        for (int i = 0; i < 4; ++i) {
            const int r = wid * 32 + i * 8 + st_r;
            const int gsrc = (st_g ^ (r & 7)) << 3;
            const u16* srcA = wsA + (size_t)(m0 + r) * K + k0 + gsrc;
            const u16* srcB = wsW + (size_t)(n0 + r) * K + k0 + gsrc;
            __builtin_amdgcn_global_load_lds(
                (const __attribute__((address_space(1))) void*)srcA,
                (__attribute__((address_space(3))) void*)&sA[(wid * 32 + i * 8) * BK],
                16, 0, 0);
            __builtin_amdgcn_global_load_lds(
                (const __attribute__((address_space(1))) void*)srcB,
                (__attribute__((address_space(3))) void*)&sB[(wid * 32 + i * 8) * BK],
                16, 0, 0);
        }

        __syncthreads();

        #pragma unroll
        for (int sub = 0; sub < 2; ++sub) {
            const int kch = (sub << 2) + fq;
            bf16x8 af[4], bfg[4];
            #pragma unroll
            for (int i = 0; i < 4; ++i) {
                const int row = wr + i * 16 + fr;
                af[i] = *(const bf16x8*)((const char*)sA + row * (BK * 2)
                                         + (((kch ^ (row & 7)) << 4)));
            }
            #pragma unroll
            for (int j = 0; j < 4; ++j) {
                const int row = wc + j * 16 + fr;
                bfg[j] = *(const bf16x8*)((const char*)sB + row * (BK * 2)
                                          + (((kch ^ (row & 7)) << 4)));
            }
            #pragma unroll
            for (int i = 0; i < 4; ++i)
                #pragma unroll
                for (int j = 0; j < 4; ++j)
                    acc[i][j] = __builtin_amdgcn_mfma_f32_16x16x32_bf16(
                        af[i], bfg[j], acc[i][j], 0, 0, 0);
        }
    }

    #pragma unroll
    for (int j = 0; j < 4; ++j) {
        const int n = n0 + wc + j * 16 + fr;
        const float bvv = Bias[n];
        #pragma unroll
        for (int i = 0; i < 4; ++i) {
            const int mb = m0 + wr + i * 16 + (fq << 2);
            #pragma unroll
            for (int r = 0; r < 4; ++r)
                Out[(size_t)(mb + r) * N + n] = acc[i][j][r] + bvv;
        }
    }
}

// ---------------- round-1 fused fallback ----------------

__global__ __launch_bounds__(THREADS, 2)
void gql_gemm(const float* __restrict__ A,
              const int* __restrict__ Wp,
              const float* __restrict__ Ws,
              const float* __restrict__ Wb,
              const float* __restrict__ Bias,
              float* __restrict__ Out,
              int M, int N, int K, int G, int gshift)
{
    __shared__ __align__(16) u16 sA[BM * BK];
    __shared__ __align__(16) u16 sB[BN * BK];

    const int tid  = threadIdx.x;
    const int lane = tid & 63;
    const int wid  = tid >> 6;

    const int nwg = gridDim.x;
    int wg = blockIdx.x;
    if ((nwg & 7) == 0) wg = (wg & 7) * (nwg >> 3) + (wg >> 3);
    const int nt     = N / BN;
    const int m0 = (wg / nt) * BM;
    const int n0 = (wg % nt) * BN;

    const int wpr = K >> 2;

    const int a_r = tid >> 4;
    const int a_c = (tid & 15) << 2;
    const int b_r = tid >> 3;
    const int b_w = (tid & 7) << 1;

    const int wr = (wid >> 1) << 6;
    const int wc = (wid & 1) << 6;
    const int fr = lane & 15;
    const int fq = lane >> 4;

    f32x4 acc[4][4] = {};

    for (int k0 = 0; k0 < K; k0 += BK) {
        __syncthreads();

        #pragma unroll
        for (int it = 0; it < 8; ++it) {
            const int row = it * 16 + a_r;
            const float4 v = *(const float4*)(A + (size_t)(m0 + row) * K + (k0 + a_c));
            u16x8 h4;
            h4[0] = f2bf(v.x); h4[1] = f2bf(v.y); h4[2] = f2bf(v.z); h4[3] = f2bf(v.w);
            const int byte = (a_c << 1) ^ ((row & 7) << 4);
            *(u16*)((char*)sA + row * (BK * 2) + byte + 0) = h4[0];
            *(u16*)((char*)sA + row * (BK * 2) + byte + 2) = h4[1];
            *(u16*)((char*)sA + row * (BK * 2) + byte + 4) = h4[2];
            *(u16*)((char*)sA + row * (BK * 2) + byte + 6) = h4[3];
        }

        const int g = k0 >> gshift;
        #pragma unroll
        for (int it = 0; it < 4; ++it) {
            const int row = it * 32 + b_r;
            const int gn  = n0 + row;
            const int2 w2 = *(const int2*)(Wp + (size_t)gn * wpr + (k0 >> 2) + b_w);
            const float s = Ws[gn * G + g];
            const float b = Wb[gn * G + g];
            u16x8 h;
            #pragma unroll
            for (int j = 0; j < 4; ++j)
                h[j]     = f2bf(fmaf((float)((w2.x >> (4 * j)) & 0xF), s, b));
            #pragma unroll
            for (int j = 0; j < 4; ++j)
                h[4 + j] = f2bf(fmaf((float)((w2.y >> (4 * j)) & 0xF), s, b));
            const int byte = (b_w << 3) ^ ((row & 7) << 4);
            *(u16x8*)((char*)sB + row * (BK * 2) + byte) = h;
        }

        __syncthreads();

        #pragma unroll
        for (int sub = 0; sub < 2; ++sub) {
            const int kch = (sub << 2) + fq;
            bf16x8 af[4], bfg[4];
            #pragma unroll
            for (int i = 0; i < 4; ++i) {
                const int row = wr + i * 16 + fr;
                af[i] = *(const bf16x8*)((const char*)sA + row * (BK * 2)
                                         + ((kch << 4) ^ ((row & 7) << 4)));
            }
            #pragma unroll
            for (int j = 0; j < 4; ++j) {
                const int row = wc + j * 16 + fr;
                bfg[j] = *(const bf16x8*)((const char*)sB + row * (BK * 2)
                                          + ((kch << 4) ^ ((row & 7) << 4)));
            }
            #pragma unroll
            for (int i = 0; i < 4; ++i)
                #pragma unroll
                for (int j = 0; j < 4; ++j)
                    acc[i][j] = __builtin_amdgcn_mfma_f32_16x16x32_bf16(
                        af[i], bfg[j], acc[i][j], 0, 0, 0);
        }
    }

    #pragma unroll
    for (int j = 0; j < 4; ++j) {
        const int n = n0 + wc + j * 16 + fr;
        const float bvv = Bias[n];
        #pragma unroll
        for (int i = 0; i < 4; ++i) {
            const int mb = m0 + wr + i * 16 + (fq << 2);
            #pragma unroll
            for (int r = 0; r < 4; ++r)
                Out[(size_t)(mb + r) * N + n] = acc[i][j][r] + bvv;
        }
    }
}

extern "C" void kernel_launch(void* const* d_in, const int* in_sizes, int n_in,
                              void* d_out, int out_size, void* d_ws, size_t ws_size,
                              hipStream_t stream) {
    const float* A    = (const float*)d_in[0];
    const int*   Wp   = (const int*)d_in[1];
    const float* Ws   = (const float*)d_in[2];
    const float* Wb   = (const float*)d_in[3];
    const float* Bias = (const float*)d_in[4];
    float* Out = (float*)d_out;

    const int OUT  = in_sizes[4];
    const int OG   = in_sizes[2];          // OUT * G
    const int G    = OG / OUT;             // 16
    const int cols = in_sizes[1] / OG;     // 64
    const int IN   = G * cols * 4;         // 4096
    const int M    = in_sizes[0] / IN;     // 4096

    const int gk = IN / G;                 // 256
    int gshift = 0;
    while ((1 << gshift) < gk) ++gshift;   // 8

    int kshift = 0;
    while ((1 << kshift) < IN) ++kshift;   // 12

    const size_t needXq = (size_t)M * IN;
    const size_t needWq = (size_t)OUT * IN;
    const size_t needSc = (size_t)M * 8 + (size_t)OUT * 8;
    const size_t needI8 = needXq + needWq + needSc;

    const bool kpow2  = ((IN & (IN - 1)) == 0);
    const bool gkpow2 = ((1 << gshift) == gk);

    if (ws_size >= needI8 && kpow2 && gkpow2 && (IN % 128) == 0 && IN >= 256 &&
        (M % 256) == 0 && (OUT % 256) == 0 && (gk % 16) == 0) {
        char*  xq   = (char*)d_ws;
        char*  wq   = (char*)d_ws + needXq;
        float* sx   = (float*)((char*)d_ws + needXq + needWq);
        float* rsx  = sx + M;
        float* swr  = rsx + M;
        float* rswr = swr + OUT;

        rowstat_kernel<<<M, 64, 0, stream>>>(A, sx, rsx, IN);

        const size_t n16 = (size_t)M * IN / 16;
        quantX_kernel<<<(unsigned)((n16 + 255) / 256), 256, 0, stream>>>(
            A, rsx, xq, kshift, n16);

        rowscaleW_kernel<<<(OUT + 255) / 256, 256, 0, stream>>>(Ws, Wb, swr, rswr,
                                                                G, OUT);

        const int kcshift = kshift - 4;                 // log2(K/16)
        const size_t nthr = (size_t)OUT * (IN >> 4);
        quantW_row_kernel<<<(unsigned)((nthr + 255) / 256), 256, 0, stream>>>(
            Wp, Ws, Wb, rswr, wq, IN, G, gshift, kcshift, nthr);

        dim3 grid((M / 256) * (OUT / 256));
        gql_gemm_i8r<<<grid, 512, 0, stream>>>(xq, wq, swr, sx, Bias, Out,
                                               M, OUT, IN);
        return;
    }

    const size_t needA = (size_t)M * IN * 2;
    const size_t needW = (size_t)OUT * IN * 2;

    if (ws_size >= needA + needW && (IN & 7) == 0 &&
        (M % 128) == 0 && (OUT % 128) == 0 && (IN % 64) == 0) {
        u16* wsA = (u16*)d_ws;
        u16* wsW = (u16*)((char*)d_ws + needA);

        const size_t nA8 = (size_t)M * IN / 8;
        cvtA_kernel<<<(unsigned)((nA8 + 255) / 256), 256, 0, stream>>>(A, wsA, nA8);

        int kgshift = 0;
        while ((1 << kgshift) < (IN >> 3)) ++kgshift;
        const size_t nW8 = (size_t)OUT * IN / 8;
        deqW_kernel<<<(unsigned)((nW8 + 255) / 256), 256, 0, stream>>>(
            Wp, Ws, Wb, wsW, IN, G, gshift, kgshift, nW8);

        dim3 grid((M / BM) * (OUT / BN));
        gql_gemm_pre<<<grid, THREADS, 0, stream>>>(wsA, wsW, Bias, Out, M, OUT, IN);
    } else {
        dim3 grid((M / BM) * (OUT / BN));
        gql_gemm<<<grid, THREADS, 0, stream>>>(A, Wp, Ws, Wb, Bias, Out,
                                               M, OUT, IN, G, gshift);
    }
}